// Round 6
// baseline (18.007 us; speedup 1.0000x reference)
//
#include <hip/hip_runtime.h>

// Quanvolution: 4-wire RY/CNOT circuit per 2x2 patch, real amplitudes.
// State idx = i0*8 + i1*4 + i2*2 + i3 (wire w -> bit stride 8>>w).
// Thread handles FOUR patch-pairs (8 patches) at i + k*total/4 -> constant
// address offsets; all 8 loads issued upfront so one stall covers 4 circuits.
// Two patches per pair ride lo/hi of packed fp32. Variational RYs in tan form;
// the dropped cos factors form a uniform scale P = prod cos^2 applied at the end.

typedef float f32x2 __attribute__((ext_vector_type(2)));

#define REV 0.07957747155f  // 1/(4*pi): theta -> (theta/2) in revolutions

__device__ __forceinline__ float fsin(float rev) {
    float o; asm("v_sin_f32 %0, %1" : "=v"(o) : "v"(rev)); return o;
}
__device__ __forceinline__ float fcos(float rev) {
    float o; asm("v_cos_f32 %0, %1" : "=v"(o) : "v"(rev)); return o;
}
__device__ __forceinline__ f32x2 pk_fma(f32x2 a, f32x2 b, f32x2 c) {
    return __builtin_elementwise_fma(a, b, c);
}
__device__ __forceinline__ f32x2 splat(float v) { return (f32x2){v, v}; }

// s = sin(x/2), c = cos(x/2) for x in [0,1): Taylor, err < 2e-6
__device__ __forceinline__ void pk_sincos_half(f32x2 x, f32x2& s, f32x2& c) {
    f32x2 t = x * 0.5f;
    f32x2 u = t * t;
    f32x2 ps = pk_fma(u, splat(8.3333333e-3f), splat(-0.16666667f));
    s = t * pk_fma(u, ps, splat(1.0f));
    f32x2 pc = pk_fma(u, splat(-1.3888889e-3f), splat(4.1666667e-2f));
    pc = pk_fma(u, pc, splat(-0.5f));
    c = pk_fma(u, pc, splat(1.0f));
}

template <int W>
__device__ __forceinline__ void apply_ry_t(f32x2 st[16], f32x2 tb, f32x2 ntb) {
    constexpr int S = 8 >> W;
#pragma unroll
    for (int i = 0; i < 16; ++i) {
        if ((i & S) == 0) {
            f32x2 a = st[i], b = st[i | S];
            st[i]     = pk_fma(ntb, b, a);
            st[i | S] = pk_fma(tb, a, b);
        }
    }
}

template <int C, int T>
__device__ __forceinline__ void cnot(f32x2 st[16]) {
    constexpr int CS = 8 >> C, TS = 8 >> T;
#pragma unroll
    for (int i = 0; i < 16; ++i) {
        if ((i & CS) != 0 && (i & TS) == 0) {
            f32x2 t = st[i];
            st[i] = st[i | TS];
            st[i | TS] = t;
        }
    }
}

__device__ __forceinline__ void circuit_pair(float4 top, float4 bot,
                                             const f32x2 tv[8], const f32x2 ntv[8],
                                             f32x2 scale, float4& o0, float4& o1) {
    f32x2 sw[4], cw[4];
    pk_sincos_half((f32x2){top.x, top.z}, sw[0], cw[0]);
    pk_sincos_half((f32x2){top.y, top.w}, sw[1], cw[1]);
    pk_sincos_half((f32x2){bot.x, bot.z}, sw[2], cw[2]);
    pk_sincos_half((f32x2){bot.y, bot.w}, sw[3], cw[3]);

    f32x2 st[16];
    {
        f32x2 r00 = cw[0] * cw[1], r01 = cw[0] * sw[1];
        f32x2 r10 = sw[0] * cw[1], r11 = sw[0] * sw[1];
        f32x2 q00 = cw[2] * cw[3], q01 = cw[2] * sw[3];
        f32x2 q10 = sw[2] * cw[3], q11 = sw[2] * sw[3];
        st[0]  = r00 * q00; st[1]  = r00 * q01; st[2]  = r00 * q10; st[3]  = r00 * q11;
        st[4]  = r01 * q00; st[5]  = r01 * q01; st[6]  = r01 * q10; st[7]  = r01 * q11;
        st[8]  = r10 * q00; st[9]  = r10 * q01; st[10] = r10 * q10; st[11] = r10 * q11;
        st[12] = r11 * q00; st[13] = r11 * q01; st[14] = r11 * q10; st[15] = r11 * q11;
    }

    cnot<0, 1>(st); cnot<1, 2>(st); cnot<2, 3>(st);

    apply_ry_t<0>(st, tv[0], ntv[0]);
    apply_ry_t<1>(st, tv[1], ntv[1]);
    apply_ry_t<2>(st, tv[2], ntv[2]);
    apply_ry_t<3>(st, tv[3], ntv[3]);
    cnot<0, 1>(st); cnot<1, 2>(st); cnot<2, 3>(st);
    apply_ry_t<0>(st, tv[4], ntv[4]);
    apply_ry_t<1>(st, tv[5], ntv[5]);
    apply_ry_t<2>(st, tv[6], ntv[6]);
    apply_ry_t<3>(st, tv[7], ntv[7]);
    cnot<0, 1>(st); cnot<1, 2>(st); cnot<2, 3>(st);

#pragma unroll
    for (int k = 0; k < 16; ++k) st[k] = st[k] * st[k];

    f32x2 a0 = st[0] + st[1],   d0 = st[0] - st[1];
    f32x2 a1 = st[2] + st[3],   d1 = st[2] - st[3];
    f32x2 a2 = st[4] + st[5],   d2 = st[4] - st[5];
    f32x2 a3 = st[6] + st[7],   d3 = st[6] - st[7];
    f32x2 a4 = st[8] + st[9],   d4 = st[8] - st[9];
    f32x2 a5 = st[10] + st[11], d5 = st[10] - st[11];
    f32x2 a6 = st[12] + st[13], d6 = st[12] - st[13];
    f32x2 a7 = st[14] + st[15], d7 = st[14] - st[15];
    f32x2 z3 = ((d0 + d1) + (d2 + d3)) + ((d4 + d5) + (d6 + d7));
    f32x2 b0 = a0 + a1, b1 = a2 + a3, b2 = a4 + a5, b3 = a6 + a7;
    f32x2 z2 = (a0 - a1) + (a2 - a3) + (a4 - a5) + (a6 - a7);
    f32x2 z1 = (b0 - b1) + (b2 - b3);
    f32x2 z0 = (b0 + b1) - (b2 + b3);
    z0 *= scale; z1 *= scale; z2 *= scale; z3 *= scale;

    o0 = make_float4(z0.x, z1.x, z2.x, z3.x);
    o1 = make_float4(z0.y, z1.y, z2.y, z3.y);
}

template <int K>
__global__ __launch_bounds__(256) void quanv_kernel(
    const float* __restrict__ x,      // (B,1,28,28)
    const float* __restrict__ params, // (2,4) raw angles
    float* __restrict__ out,          // (B, 784)
    int chunkPairs,                   // totalPairs / K
    int chunkElems)                   // (B/K) * 784  (offset for both x and out)
{
    int i = blockIdx.x * 256 + threadIdx.x;
    if (i >= chunkPairs) return;

    int b  = i / 98;
    int q  = i - b * 98;
    int r  = q / 7;
    int cp = q - r * 7;

    // all loads upfront: one latency stall covers K circuits
    const float* base = x + (size_t)b * 784 + r * 56 + cp * 4;
    float4 L[2 * K];
#pragma unroll
    for (int k = 0; k < K; ++k) {
        const float* p = base + (size_t)k * chunkElems;
        L[2 * k]     = *reinterpret_cast<const float4*>(p);
        L[2 * k + 1] = *reinterpret_cast<const float4*>(p + 28);
    }

    // uniform variational prologue under the load shadow
    f32x2 tv[8], ntv[8];
    float P = 1.0f;
#pragma unroll
    for (int k = 0; k < 8; ++k) {
        float rev = params[k] * REV;
        float s = fsin(rev), c = fcos(rev);
        float t = s * __builtin_amdgcn_rcpf(c);
        tv[k] = splat(t);
        ntv[k] = splat(-t);
        P *= c * c;
    }
    f32x2 scale = splat(P);

    float* obase = out + ((size_t)b * 196 + r * 14 + cp * 2) * 4;
#pragma unroll
    for (int k = 0; k < K; ++k) {
        float4 o0, o1;
        circuit_pair(L[2 * k], L[2 * k + 1], tv, ntv, scale, o0, o1);
        float* op = obase + (size_t)k * chunkElems;
        reinterpret_cast<float4*>(op)[0] = o0;
        reinterpret_cast<float4*>(op)[1] = o1;
    }
}

extern "C" void kernel_launch(void* const* d_in, const int* in_sizes, int n_in,
                              void* d_out, int out_size, void* d_ws, size_t ws_size,
                              hipStream_t stream) {
    const float* x      = (const float*)d_in[0];
    const float* params = (const float*)d_in[1];
    float* out = (float*)d_out;

    int B = in_sizes[0] / 784;   // 8192

    if ((B % 4) == 0) {
        int chunkPairs = (B / 4) * 98;       // 200704
        int chunkElems = (B / 4) * 784;      // offset between chunks (x and out)
        int grid = (chunkPairs + 255) / 256; // 784 exact for B=8192
        quanv_kernel<4><<<grid, 256, 0, stream>>>(x, params, out, chunkPairs, chunkElems);
    } else {
        int chunkPairs = B * 98;
        int grid = (chunkPairs + 255) / 256;
        quanv_kernel<1><<<grid, 256, 0, stream>>>(x, params, out, chunkPairs, B * 784);
    }
}

// Round 8
// 16.201 us; speedup vs baseline: 1.1115x; 1.1115x over previous
//
#include <hip/hip_runtime.h>

// Quanvolution: 4-wire RY/CNOT circuit per 2x2 patch, real amplitudes.
// State idx = i0*8 + i1*4 + i2*2 + i3 (wire w -> bit stride 8>>w).
// Two patches per thread ride lo/hi halves of packed fp32 (v_pk_*_f32).
// Variational RYs in tan form (2 pk_fma/butterfly); dropped cos factors form
// the uniform scale P = prod cos^2 applied at the end. Data-encoding sincos
// via packed polynomial (arg in [0,0.5)). Uniform tan prologue computed
// per-thread under the global-load shadow (no LDS, no barrier).

typedef float f32x2 __attribute__((ext_vector_type(2)));
typedef float f32x4 __attribute__((ext_vector_type(4)));

#define REV 0.07957747155f  // 1/(4*pi): theta -> (theta/2) in revolutions

__device__ __forceinline__ float fsin(float rev) {
    float o; asm("v_sin_f32 %0, %1" : "=v"(o) : "v"(rev)); return o;
}
__device__ __forceinline__ float fcos(float rev) {
    float o; asm("v_cos_f32 %0, %1" : "=v"(o) : "v"(rev)); return o;
}
__device__ __forceinline__ f32x2 pk_fma(f32x2 a, f32x2 b, f32x2 c) {
    return __builtin_elementwise_fma(a, b, c);
}
__device__ __forceinline__ f32x2 splat(float v) { return (f32x2){v, v}; }

// s = sin(x/2), c = cos(x/2) for x in [0,1): Taylor, err < 2e-6
__device__ __forceinline__ void pk_sincos_half(f32x2 x, f32x2& s, f32x2& c) {
    f32x2 t = x * 0.5f;
    f32x2 u = t * t;
    f32x2 ps = pk_fma(u, splat(8.3333333e-3f), splat(-0.16666667f));
    s = t * pk_fma(u, ps, splat(1.0f));
    f32x2 pc = pk_fma(u, splat(-1.3888889e-3f), splat(4.1666667e-2f));
    pc = pk_fma(u, pc, splat(-0.5f));
    c = pk_fma(u, pc, splat(1.0f));
}

template <int W>
__device__ __forceinline__ void apply_ry_t(f32x2 st[16], f32x2 tb, f32x2 ntb) {
    constexpr int S = 8 >> W;
#pragma unroll
    for (int i = 0; i < 16; ++i) {
        if ((i & S) == 0) {
            f32x2 a = st[i], b = st[i | S];
            st[i]     = pk_fma(ntb, b, a);
            st[i | S] = pk_fma(tb, a, b);
        }
    }
}

template <int C, int T>
__device__ __forceinline__ void cnot(f32x2 st[16]) {
    constexpr int CS = 8 >> C, TS = 8 >> T;
#pragma unroll
    for (int i = 0; i < 16; ++i) {
        if ((i & CS) != 0 && (i & TS) == 0) {
            f32x2 t = st[i];
            st[i] = st[i | TS];
            st[i | TS] = t;
        }
    }
}

template <bool GUARD>
__global__ __launch_bounds__(256, 6) void quanv_kernel(
    const float* __restrict__ x,      // (B,1,28,28)
    const float* __restrict__ params, // (2,4) raw angles
    float* __restrict__ out,          // (B, 784)
    int totalPairs)                   // B*98 (patch pairs)
{
    int i = blockIdx.x * 256 + threadIdx.x;
    if (GUARD && i >= totalPairs) return;

    int b  = i / 98;
    int q  = i - b * 98;
    int r  = q / 7;
    int cp = q - r * 7;   // pair index: cols 4*cp .. 4*cp+3

    // issue loads first; uniform prologue hides under their latency
    const float* base = x + (size_t)b * 784 + r * 56 + cp * 4;
    f32x4 top = *reinterpret_cast<const f32x4*>(base);
    f32x4 bot = *reinterpret_cast<const f32x4*>(base + 28);

    // batch-invariant variational tans + norm factor (params -> s_loads)
    f32x2 tv[8], ntv[8];
    float P = 1.0f;
#pragma unroll
    for (int k = 0; k < 8; ++k) {
        float rev = params[k] * REV;
        float s = fsin(rev), c = fcos(rev);
        float t = s * __builtin_amdgcn_rcpf(c);
        tv[k] = splat(t);
        ntv[k] = splat(-t);
        P *= c * c;
    }
    f32x2 scale = splat(P);

    // lo half = circuit 0, hi half = circuit 1
    f32x2 sw[4], cw[4];
    pk_sincos_half((f32x2){top.x, top.z}, sw[0], cw[0]);
    pk_sincos_half((f32x2){top.y, top.w}, sw[1], cw[1]);
    pk_sincos_half((f32x2){bot.x, bot.z}, sw[2], cw[2]);
    pk_sincos_half((f32x2){bot.y, bot.w}, sw[3], cw[3]);

    // product state after data-encoding RYs on |0000>
    f32x2 st[16];
    {
        f32x2 r00 = cw[0] * cw[1], r01 = cw[0] * sw[1];
        f32x2 r10 = sw[0] * cw[1], r11 = sw[0] * sw[1];
        f32x2 q00 = cw[2] * cw[3], q01 = cw[2] * sw[3];
        f32x2 q10 = sw[2] * cw[3], q11 = sw[2] * sw[3];
        st[0]  = r00 * q00; st[1]  = r00 * q01; st[2]  = r00 * q10; st[3]  = r00 * q11;
        st[4]  = r01 * q00; st[5]  = r01 * q01; st[6]  = r01 * q10; st[7]  = r01 * q11;
        st[8]  = r10 * q00; st[9]  = r10 * q01; st[10] = r10 * q10; st[11] = r10 * q11;
        st[12] = r11 * q00; st[13] = r11 * q01; st[14] = r11 * q10; st[15] = r11 * q11;
    }

    cnot<0, 1>(st); cnot<1, 2>(st); cnot<2, 3>(st);

    apply_ry_t<0>(st, tv[0], ntv[0]);
    apply_ry_t<1>(st, tv[1], ntv[1]);
    apply_ry_t<2>(st, tv[2], ntv[2]);
    apply_ry_t<3>(st, tv[3], ntv[3]);
    cnot<0, 1>(st); cnot<1, 2>(st); cnot<2, 3>(st);
    apply_ry_t<0>(st, tv[4], ntv[4]);
    apply_ry_t<1>(st, tv[5], ntv[5]);
    apply_ry_t<2>(st, tv[6], ntv[6]);
    apply_ry_t<3>(st, tv[7], ntv[7]);
    cnot<0, 1>(st); cnot<1, 2>(st); cnot<2, 3>(st);

#pragma unroll
    for (int k = 0; k < 16; ++k) st[k] = st[k] * st[k];

    // single-bit parity sums with shared subsums; uniform P-scale normalizes
    f32x2 a0 = st[0] + st[1],   d0 = st[0] - st[1];
    f32x2 a1 = st[2] + st[3],   d1 = st[2] - st[3];
    f32x2 a2 = st[4] + st[5],   d2 = st[4] - st[5];
    f32x2 a3 = st[6] + st[7],   d3 = st[6] - st[7];
    f32x2 a4 = st[8] + st[9],   d4 = st[8] - st[9];
    f32x2 a5 = st[10] + st[11], d5 = st[10] - st[11];
    f32x2 a6 = st[12] + st[13], d6 = st[12] - st[13];
    f32x2 a7 = st[14] + st[15], d7 = st[14] - st[15];
    f32x2 z3 = ((d0 + d1) + (d2 + d3)) + ((d4 + d5) + (d6 + d7));
    f32x2 b0 = a0 + a1, b1 = a2 + a3, b2 = a4 + a5, b3 = a6 + a7;
    f32x2 z2 = (a0 - a1) + (a2 - a3) + (a4 - a5) + (a6 - a7);
    f32x2 z1 = (b0 - b1) + (b2 - b3);
    f32x2 z0 = (b0 + b1) - (b2 + b3);
    z0 *= scale; z1 *= scale; z2 *= scale; z3 *= scale;

    float* op = out + ((size_t)b * 196 + r * 14 + cp * 2) * 4;
    __builtin_nontemporal_store((f32x4){z0.x, z1.x, z2.x, z3.x},
                                reinterpret_cast<f32x4*>(op));
    __builtin_nontemporal_store((f32x4){z0.y, z1.y, z2.y, z3.y},
                                reinterpret_cast<f32x4*>(op) + 1);
}

extern "C" void kernel_launch(void* const* d_in, const int* in_sizes, int n_in,
                              void* d_out, int out_size, void* d_ws, size_t ws_size,
                              hipStream_t stream) {
    const float* x      = (const float*)d_in[0];
    const float* params = (const float*)d_in[1];
    float* out = (float*)d_out;

    int B = in_sizes[0] / 784;   // 8192
    int totalPairs = B * 98;     // 802816

    if ((totalPairs & 255) == 0) {
        quanv_kernel<false><<<totalPairs / 256, 256, 0, stream>>>(x, params, out, totalPairs);
    } else {
        quanv_kernel<true><<<(totalPairs + 255) / 256, 256, 0, stream>>>(x, params, out, totalPairs);
    }
}